// Round 1
// 209.088 us; speedup vs baseline: 1.0316x; 1.0316x over previous
//
#include <hip/hip_runtime.h>

typedef unsigned long long ull;

#define NUM_K   512
#define DIM     64
#define N_ROWS  (32 * 64 * 64)     // 131072 rows
#define HW      4096               // 64*64
#define CHW     (64 * 4096)        // per-batch stride (C*H*W)

// Output buffer float32, flat layout = reference return order:
//   [ discrete (131072) | quantized NCHW (8388608) | loss (1) ]
#define IDX_OFF  0
#define Q_OFF    N_ROWS
#define LOSS_OFF (N_ROWS + 32 * 64 * 4096)   // 8519680

#define TILE_R  256    // rows per block (512 blocks)
#define RS      68     // LDS x row stride (dwords), 16B-aligned rows
#define CAP     16     // candidate list capacity per row
// Window: |approx_t - exact_t| <= (2^-8 + 2^-8 + 2^-16)*maxx_r*sumw_c + eps
// (bf16 RN rel err 2^-8 per operand; bf16*bf16 exact in f32; accum/rounding
//  terms ~1.6e-5 total). Required 2*bound ~ 0.0157*maxx*sumw; use 0.018 + 2.5e-4.
#define WK1     0.018f
#define WK2     2.5e-4f

typedef __attribute__((ext_vector_type(8))) short bf16x8;   // 8 bf16 = 4 VGPRs
typedef __attribute__((ext_vector_type(4))) float f32x4;

// numpy pairwise_sum (n=64) of squares (validated bit-exact vs reference)
#define NP_SUMSQ64(SRC, DST)                                                   \
    do {                                                                       \
        float r_[8];                                                           \
        _Pragma("unroll")                                                      \
        for (int j_ = 0; j_ < 8; ++j_) r_[j_] = __fmul_rn((SRC)[j_], (SRC)[j_]); \
        _Pragma("unroll")                                                      \
        for (int i_ = 8; i_ < 64; i_ += 8) {                                   \
            _Pragma("unroll")                                                  \
            for (int j_ = 0; j_ < 8; ++j_)                                     \
                r_[j_] = __fadd_rn(r_[j_], __fmul_rn((SRC)[i_ + j_], (SRC)[i_ + j_])); \
        }                                                                      \
        (DST) = __fadd_rn(__fadd_rn(__fadd_rn(r_[0], r_[1]), __fadd_rn(r_[2], r_[3])), \
                          __fadd_rn(__fadd_rn(r_[4], r_[5]), __fadd_rn(r_[6], r_[7]))); \
    } while (0)

__device__ __forceinline__ unsigned bf16rn(float f) {   // RN-to-nearest-even, finite inputs
    unsigned u = __float_as_uint(f);
    return (u + 0x7fffu + ((u >> 16) & 1u)) >> 16;
}
__device__ __forceinline__ unsigned pk2(float lo, float hi) {
    return bf16rn(lo) | (bf16rn(hi) << 16);
}

// Exact reference-semantics distance: sequential fp32 FMA chain over d
// (OpenBLAS sgemm semantics, validated bit-exact in prior session).
__device__ __forceinline__ float evald(const float* __restrict__ xr,
                                       const float* __restrict__ wc,
                                       float A, float w2c) {
    float m = 0.0f;
    #pragma unroll
    for (int d = 0; d < DIM; ++d) m = __fmaf_rn(xr[d], wc[d], m);
    return __fadd_rn(__fsub_rn(A, __fmul_rn(2.0f, m)), w2c);
}

__global__ __launch_bounds__(512, 2) void vq_mfma(const float* __restrict__ x_in,
                                                  const float* __restrict__ weight,
                                                  double* __restrict__ lslots,
                                                  float* __restrict__ out) {
    __shared__ float xlds[TILE_R * RS];          // 69632 B fp32 x tile (row-major)
    __shared__ unsigned bfr[NUM_K * 32];         // 65536 B bf16 B-frags, frag-linear
    __shared__ float w2all[NUM_K];               // exact ||w||^2 (pairwise chain)
    __shared__ float w2h[NUM_K];                 // 0.5*||w||^2 (exact scale)
    __shared__ float sumw[NUM_K];                // sum|w| (+slack) for window
    __shared__ float Arow[TILE_R];
    __shared__ float maxx[TILE_R];
    __shared__ int   cntL[TILE_R];
    __shared__ unsigned short listL[TILE_R * CAP];
    __shared__ int   ilds[TILE_R];
    __shared__ float wsum[8];

    const int tid   = threadIdx.x;
    const int lane  = tid & 63;
    const int wid   = tid >> 6;        // 8 waves; wave owns rows [wbase, wbase+32)
    const int wbase = wid * 32;
    const int qid   = lane >> 4;       // lane quarter 0..3
    const int l15   = lane & 15;

    const int rowbase = blockIdx.x * TILE_R;
    const int b       = rowbase >> 12;
    const int hw0     = rowbase & 4095;
    const float* xb   = x_in + (size_t)b * CHW + hw0;

    // ---- stage x: coalesced scalar loads (lanes = consecutive rows), f4 LDS write ----
    #pragma unroll
    for (int it = 0; it < 8; ++it) {
        int id  = it * 512 + tid;
        int row = id & 255, g = id >> 8;               // g = float4 group 0..15
        const float* gp = xb + g * 4 * HW + row;
        float4 v = make_float4(gp[0], gp[HW], gp[2 * HW], gp[3 * HW]);
        *(float4*)&xlds[row * RS + g * 4] = v;
    }

    // ---- stage w: one code per thread: sums + bf16 fragment granules ----
    {
        const int c = tid;                             // 512 threads = 512 codes
        const float* wr = weight + c * DIM;
        float wv[DIM];
        #pragma unroll
        for (int d = 0; d < DIM; d += 4) {
            float4 t4 = *(const float4*)&wr[d];
            wv[d] = t4.x; wv[d + 1] = t4.y; wv[d + 2] = t4.z; wv[d + 3] = t4.w;
        }
        float s; NP_SUMSQ64(wv, s);
        w2all[c] = s;
        w2h[c]   = 0.5f * s;
        float sa = 0.0f;
        #pragma unroll
        for (int d = 0; d < DIM; ++d) sa = __fadd_rn(sa, fabsf(wv[d]));
        sumw[c] = sa * 1.0002f + 1e-7f;                // cover fp32 sum rounding
        // frag-linear layout: tile j=c>>4 (512 dwords), half h (256 dwords),
        // lane-slot l = (c&15) | ((g&3)<<4) at l*4 dwords; k = 32h + 8*(g&3) + t
        const int tb = (c >> 4) * 512;
        const int ls = (c & 15) * 4;
        #pragma unroll
        for (int g = 0; g < 8; ++g) {
            int base = tb + (g >> 2) * 256 + (g & 3) * 64 + ls;
            uint4 pw = make_uint4(pk2(wv[8 * g + 0], wv[8 * g + 1]),
                                  pk2(wv[8 * g + 2], wv[8 * g + 3]),
                                  pk2(wv[8 * g + 4], wv[8 * g + 5]),
                                  pk2(wv[8 * g + 6], wv[8 * g + 7]));
            *(uint4*)&bfr[base] = pw;
        }
    }
    if (tid < TILE_R) cntL[tid] = 0;
    __syncthreads();

    // ---- per-row A (pairwise, bit-exact) + maxabs ----
    if (tid < TILE_R) {
        const float* src = &xlds[tid * RS];
        float s; NP_SUMSQ64(src, s);
        Arow[tid] = s;
        float mx = 0.0f;
        #pragma unroll
        for (int d = 0; d < DIM; ++d) mx = fmaxf(mx, fabsf(src[d]));
        maxx[tid] = mx;
    }

    // ---- A fragments in registers: 2 row-tiles x 2 K-halves ----
    // Same (quarter,t)->k map as B staging => dot product correct under any
    // consistent internal k-permutation.
    bf16x8 afr[2][2];
    #pragma unroll
    for (int rt = 0; rt < 2; ++rt) {
        int r = wbase + 16 * rt + l15;
        #pragma unroll
        for (int h = 0; h < 2; ++h) {
            int kb = h * 32 + qid * 8;
            float4 xa  = *(const float4*)&xlds[r * RS + kb];
            float4 xc  = *(const float4*)&xlds[r * RS + kb + 4];
            union { unsigned u[4]; bf16x8 v; } cv;
            cv.u[0] = pk2(xa.x, xa.y); cv.u[1] = pk2(xa.z, xa.w);
            cv.u[2] = pk2(xc.x, xc.y); cv.u[3] = pk2(xc.z, xc.w);
            afr[rt][h] = cv.v;
        }
    }
    __syncthreads();   // Arow/maxx computed by other waves' threads

    float wk1r[2][4], tmin[2][4];
    #pragma unroll
    for (int rt = 0; rt < 2; ++rt)
        #pragma unroll
        for (int rg = 0; rg < 4; ++rg) {
            wk1r[rt][rg] = WK1 * maxx[wbase + 16 * rt + 4 * qid + rg];
            tmin[rt][rg] = 3.4e38f;
        }

    const int lane4 = lane * 4;
    for (int q = 0; q < 4; ++q) {          // 4 chunks x 128 codes
        f32x4 acc[2][8] = {};
        #pragma unroll
        for (int j = 0; j < 8; ++j) {
            int tb2 = (q * 8 + j) * 512;
            bf16x8 bb0 = *(const bf16x8*)&bfr[tb2 + lane4];          // k 0..31
            bf16x8 bb1 = *(const bf16x8*)&bfr[tb2 + 256 + lane4];    // k 32..63
            acc[0][j] = __builtin_amdgcn_mfma_f32_16x16x32_bf16(afr[0][0], bb0, acc[0][j], 0, 0, 0);
            acc[0][j] = __builtin_amdgcn_mfma_f32_16x16x32_bf16(afr[0][1], bb1, acc[0][j], 0, 0, 0);
            acc[1][j] = __builtin_amdgcn_mfma_f32_16x16x32_bf16(afr[1][0], bb0, acc[1][j], 0, 0, 0);
            acc[1][j] = __builtin_amdgcn_mfma_f32_16x16x32_bf16(afr[1][1], bb1, acc[1][j], 0, 0, 0);
        }

        // t = w2/2 - m  (dist = A + 2t, monotone) ; per-(rt,reg) chunk min
        float swv[8], tl[2][4];
        #pragma unroll
        for (int rt = 0; rt < 2; ++rt)
            #pragma unroll
            for (int rg = 0; rg < 4; ++rg) tl[rt][rg] = 3.4e38f;
        #pragma unroll
        for (int j = 0; j < 8; ++j) {
            int c = q * 128 + j * 16 + l15;
            float w2hv = w2h[c];
            swv[j] = sumw[c];
            #pragma unroll
            for (int rt = 0; rt < 2; ++rt)
                #pragma unroll
                for (int rg = 0; rg < 4; ++rg) {
                    float t = w2hv - acc[rt][j][rg];
                    acc[rt][j][rg] = t;
                    tl[rt][rg] = fminf(tl[rt][rg], t);
                }
        }
        // row min across the 16 lanes of each quarter
        #pragma unroll
        for (int mk = 1; mk <= 8; mk <<= 1)
            #pragma unroll
            for (int rt = 0; rt < 2; ++rt)
                #pragma unroll
                for (int rg = 0; rg < 4; ++rg)
                    tl[rt][rg] = fminf(tl[rt][rg], __shfl_xor(tl[rt][rg], mk));
        float thr0[2][4];
        #pragma unroll
        for (int rt = 0; rt < 2; ++rt)
            #pragma unroll
            for (int rg = 0; rg < 4; ++rg) {
                tmin[rt][rg] = fminf(tmin[rt][rg], tl[rt][rg]);
                thr0[rt][rg] = tmin[rt][rg] + WK2;
            }
        float swmax = swv[0];
        #pragma unroll
        for (int j = 1; j < 8; ++j) swmax = fmaxf(swmax, swv[j]);

        // collect candidates within window of running min (superset of final set)
        #pragma unroll
        for (int rt = 0; rt < 2; ++rt)
            #pragma unroll
            for (int rg = 0; rg < 4; ++rg) {
                if (tl[rt][rg] <= __fmaf_rn(wk1r[rt][rg], swmax, thr0[rt][rg])) {
                    #pragma unroll
                    for (int j = 0; j < 8; ++j) {
                        if (acc[rt][j][rg] <= __fmaf_rn(wk1r[rt][rg], swv[j], thr0[rt][rg])) {
                            int r  = wbase + 16 * rt + 4 * qid + rg;
                            int c  = q * 128 + j * 16 + l15;
                            int cn = atomicAdd(&cntL[r], 1);
                            if (cn < CAP) listL[r * CAP + cn] = (unsigned short)c;
                        }
                    }
                }
            }
    }

    __syncthreads();   // candidate lists visible

    // ---- exact rescue: reference fp32 chain on candidates; smallest-idx ties ----
    if (lane < 32) {
        const int r   = wbase + lane;
        const int cnt = cntL[r];
        if (cnt >= 1 && cnt <= CAP) {
            const float* xr = &xlds[r * RS];
            const float  A  = Arow[r];
            float bd = 3.4e38f; int bi = 1 << 30;
            for (int t2 = 0; t2 < cnt; ++t2) {
                int c = listL[r * CAP + t2];
                float d2 = evald(xr, weight + c * DIM, A, w2all[c]);
                if (d2 < bd || (d2 == bd && c < bi)) { bd = d2; bi = c; }
            }
            ilds[r] = bi;
            out[IDX_OFF + rowbase + r] = (float)bi;
        }
    }
    // cooperative exact full scan for overflow rows (rare; correctness backstop)
    for (int rr = 0; rr < 32; ++rr) {
        int r   = wbase + rr;
        int cnt = cntL[r];
        if (cnt < 1 || cnt > CAP) {
            const float* xr = &xlds[r * RS];
            const float  A  = Arow[r];
            float bd = 3.4e38f; int bi = 1 << 30;
            #pragma unroll
            for (int t2 = 0; t2 < 8; ++t2) {
                int c = t2 * 64 + lane;
                float d2 = evald(xr, weight + c * DIM, A, w2all[c]);
                if (d2 < bd || (d2 == bd && c < bi)) { bd = d2; bi = c; }
            }
            ull key = ((ull)__float_as_uint(bd) << 32) | (unsigned)bi;
            #pragma unroll
            for (int mk = 1; mk <= 32; mk <<= 1) {
                ull o = __shfl_xor(key, mk);
                if (o < key) key = o;
            }
            if (lane == 0) {
                int bi2 = (int)(key & 0xffffffffu);
                ilds[r] = bi2;
                out[IDX_OFF + rowbase + r] = (float)bi2;
            }
        }
    }
    __syncthreads();   // ilds visible

    // ---- quantize epilogue + loss (exact reference semantics, as validated) ----
    const int row = wbase + (lane & 31);
    const int dh  = (lane >> 5) << 5;           // 0 or 32
    const float* xr2 = &xlds[row * RS + dh];
    const float* wr2 = weight + ilds[row] * DIM + dh;
    float* ob = out + Q_OFF + (size_t)b * CHW + hw0 + row;
    float lsum = 0.0f;
    #pragma unroll
    for (int t2 = 0; t2 < 8; ++t2) {
        float4 xv  = *(const float4*)&xr2[4 * t2];
        float4 wv2 = *(const float4*)&wr2[4 * t2];
        float dd;
        dd = __fsub_rn(wv2.x, xv.x); ob[(size_t)(dh + 4 * t2 + 0) * HW] = __fadd_rn(xv.x, dd); lsum = fmaf(dd, dd, lsum);
        dd = __fsub_rn(wv2.y, xv.y); ob[(size_t)(dh + 4 * t2 + 1) * HW] = __fadd_rn(xv.y, dd); lsum = fmaf(dd, dd, lsum);
        dd = __fsub_rn(wv2.z, xv.z); ob[(size_t)(dh + 4 * t2 + 2) * HW] = __fadd_rn(xv.z, dd); lsum = fmaf(dd, dd, lsum);
        dd = __fsub_rn(wv2.w, xv.w); ob[(size_t)(dh + 4 * t2 + 3) * HW] = __fadd_rn(xv.w, dd); lsum = fmaf(dd, dd, lsum);
    }
    #pragma unroll
    for (int off = 32; off > 0; off >>= 1) lsum += __shfl_down(lsum, off);
    if (lane == 0) wsum[wid] = lsum;
    __syncthreads();
    if (tid == 0) {
        double s = 0.0;
        #pragma unroll
        for (int i = 0; i < 8; ++i) s += (double)wsum[i];
        lslots[blockIdx.x] = s;
    }
}

__global__ void vq_finalize4(const double* __restrict__ lslots,
                             float* __restrict__ out) {
    double s = 0.0;
    for (int i = threadIdx.x; i < 512; i += 64) s += lslots[i];
    #pragma unroll
    for (int off = 32; off > 0; off >>= 1) s += __shfl_down(s, off);
    if (threadIdx.x == 0) {
        double m = s / 8388608.0;
        out[LOSS_OFF] = (float)(m + 0.25 * m);   // q_latent + 0.25 * e_latent
    }
}

// ---------------- fallback (R5-validated fused path, used only if ws tiny) ----
__global__ void vq_zero(double* __restrict__ loss_acc) {
    if (threadIdx.x == 0) *loss_acc = 0.0;
}

__global__ __launch_bounds__(256) void vq_fused(const float* __restrict__ x_in,
                                                const float* __restrict__ weight,
                                                double* __restrict__ loss_acc,
                                                float* __restrict__ out) {
    __shared__ float w2s[NUM_K];
    for (int k = threadIdx.x; k < NUM_K; k += 256) {
        const float* wk = weight + k * DIM;
        float s; NP_SUMSQ64(wk, s);
        w2s[k] = s;
    }
    __syncthreads();

    const int n  = blockIdx.x * 256 + threadIdx.x;
    const int b  = n >> 12;
    const int hw = n & 4095;
    const float* xp = x_in + b * CHW + hw;
    float x[DIM];
    #pragma unroll
    for (int d = 0; d < DIM; ++d) x[d] = xp[d * HW];

    float A; NP_SUMSQ64(x, A);

    float best = 3.4e38f;
    int   bi   = 0;
    for (int k = 0; k < NUM_K; k += 4) {
        const float* w0 = weight + k * DIM;
        float m0 = 0.f, m1 = 0.f, m2 = 0.f, m3 = 0.f;
        #pragma unroll
        for (int d = 0; d < DIM; ++d) {
            float xd = x[d];
            m0 = __fmaf_rn(xd, w0[d],           m0);
            m1 = __fmaf_rn(xd, w0[DIM + d],     m1);
            m2 = __fmaf_rn(xd, w0[2 * DIM + d], m2);
            m3 = __fmaf_rn(xd, w0[3 * DIM + d], m3);
        }
        float d0 = __fadd_rn(__fsub_rn(A, __fmul_rn(2.0f, m0)), w2s[k]);
        float d1 = __fadd_rn(__fsub_rn(A, __fmul_rn(2.0f, m1)), w2s[k + 1]);
        float d2 = __fadd_rn(__fsub_rn(A, __fmul_rn(2.0f, m2)), w2s[k + 2]);
        float d3 = __fadd_rn(__fsub_rn(A, __fmul_rn(2.0f, m3)), w2s[k + 3]);
        if (d0 < best) { best = d0; bi = k; }
        if (d1 < best) { best = d1; bi = k + 1; }
        if (d2 < best) { best = d2; bi = k + 2; }
        if (d3 < best) { best = d3; bi = k + 3; }
    }
    const int idx = bi;

    out[IDX_OFF + n] = (float)idx;
    const float* qrow = weight + idx * DIM;
    float* oq = out + Q_OFF + b * CHW + hw;
    float lsum = 0.0f;
    #pragma unroll
    for (int d = 0; d < DIM; ++d) {
        float xd   = xp[d * HW];
        float diff = __fsub_rn(qrow[d], xd);
        oq[d * HW] = __fadd_rn(xd, diff);
        lsum = fmaf(diff, diff, lsum);
    }
    #pragma unroll
    for (int off = 32; off > 0; off >>= 1) lsum += __shfl_down(lsum, off);
    __shared__ float wsum[4];
    if ((threadIdx.x & 63) == 0) wsum[threadIdx.x >> 6] = lsum;
    __syncthreads();
    if (threadIdx.x == 0)
        atomicAdd(loss_acc, (double)((wsum[0] + wsum[1]) + (wsum[2] + wsum[3])));
}

__global__ void vq_finalize(const double* __restrict__ loss_acc,
                            float* __restrict__ out) {
    double m = *loss_acc / 8388608.0;
    out[LOSS_OFF] = (float)(m + 0.25 * m);
}

extern "C" void kernel_launch(void* const* d_in, const int* in_sizes, int n_in,
                              void* d_out, int out_size, void* d_ws, size_t ws_size,
                              hipStream_t stream) {
    const float* x = (const float*)d_in[0];    // inputs  [32,64,64,64] NCHW fp32
    const float* w = (const float*)d_in[1];    // weight  [512,64] fp32
    float* out = (float*)d_out;

    if (ws_size >= 512 * sizeof(double)) {
        double* lslots = (double*)d_ws;        // 4 KB: per-block loss partials
        vq_mfma<<<N_ROWS / TILE_R, 512, 0, stream>>>(x, w, lslots, out);
        vq_finalize4<<<1, 64, 0, stream>>>(lslots, out);
    } else {
        double* loss_acc = (double*)d_ws;      // 8 bytes
        vq_zero<<<1, 64, 0, stream>>>(loss_acc);
        vq_fused<<<512, 256, 0, stream>>>(x, w, loss_acc, out);
        vq_finalize<<<1, 1, 0, stream>>>(loss_acc, out);
    }
}

// Round 2
// 169.264 us; speedup vs baseline: 1.2744x; 1.2353x over previous
//
#include <hip/hip_runtime.h>

typedef unsigned long long ull;

#define NUM_K   512
#define DIM     64
#define N_ROWS  (32 * 64 * 64)     // 131072 rows
#define HW      4096               // 64*64
#define CHW     (64 * 4096)        // per-batch stride (C*H*W)

// Output buffer float32, flat layout = reference return order:
//   [ discrete (131072) | quantized NCHW (8388608) | loss (1) ]
#define IDX_OFF  0
#define Q_OFF    N_ROWS
#define LOSS_OFF (N_ROWS + 32 * 64 * 4096)   // 8519680

#define TILE_R  256    // rows per block (512 blocks, exactly 2/CU resident)
#define RS      68     // LDS x row stride (dwords), 16B-aligned rows
#define CAP     8      // candidate list capacity per row (split-bf16: cnt~1)

// Split-bf16 window: |t_hat - t_exact| <= ~(3.5*2^-16)*maxx_r*sumw_c
//   + mfma-accum (<=192*2^-24*maxx*sumw) ~ 6.5e-5*maxx*sumw one-sided.
// Two-sided handled via (sumw_c + running max sumw). WK1S=1e-4 gives 1.5x margin.
// WK2S covers the dist<->t reordering rounding (~3.8e-6) with 5x margin.
#define WK1S    1.0e-4f
#define WK2S    2.0e-5f

// Workspace layout (dwords): [0,16384) hi frags | [16384,32768) lo frags |
//   [32768,33280) w2all | [33280,33792) sumw | bytes 135168+: 512 lslots (double)
#define WS_FRAG_LO   16384
#define WS_W2_OFF    32768
#define WS_SW_OFF    33280
#define WS_LSL_BYTE  135168
#define WS_NEED      139264

typedef __attribute__((ext_vector_type(8))) short bf16x8;   // 8 bf16 = 4 VGPRs
typedef __attribute__((ext_vector_type(4))) float f32x4;

// numpy pairwise_sum (n=64) of squares (validated bit-exact vs reference)
#define NP_SUMSQ64(SRC, DST)                                                   \
    do {                                                                       \
        float r_[8];                                                           \
        _Pragma("unroll")                                                      \
        for (int j_ = 0; j_ < 8; ++j_) r_[j_] = __fmul_rn((SRC)[j_], (SRC)[j_]); \
        _Pragma("unroll")                                                      \
        for (int i_ = 8; i_ < 64; i_ += 8) {                                   \
            _Pragma("unroll")                                                  \
            for (int j_ = 0; j_ < 8; ++j_)                                     \
                r_[j_] = __fadd_rn(r_[j_], __fmul_rn((SRC)[i_ + j_], (SRC)[i_ + j_])); \
        }                                                                      \
        (DST) = __fadd_rn(__fadd_rn(__fadd_rn(r_[0], r_[1]), __fadd_rn(r_[2], r_[3])), \
                          __fadd_rn(__fadd_rn(r_[4], r_[5]), __fadd_rn(r_[6], r_[7]))); \
    } while (0)

__device__ __forceinline__ unsigned bf16rn(float f) {   // RN-to-nearest-even, finite
    unsigned u = __float_as_uint(f);
    return (u + 0x7fffu + ((u >> 16) & 1u)) >> 16;
}
__device__ __forceinline__ float bf2f(unsigned h) { return __uint_as_float(h << 16); }
__device__ __forceinline__ unsigned pk2(float lo, float hi) {
    return bf16rn(lo) | (bf16rn(hi) << 16);
}

// Exact reference-semantics distance: sequential fp32 FMA chain over d
// (OpenBLAS sgemm semantics, validated bit-exact).
__device__ __forceinline__ float evald(const float* __restrict__ xr,
                                       const float* __restrict__ wc,
                                       float A, float w2c) {
    float m = 0.0f;
    #pragma unroll
    for (int d = 0; d < DIM; ++d) m = __fmaf_rn(xr[d], wc[d], m);
    return __fadd_rn(__fsub_rn(A, __fmul_rn(2.0f, m)), w2c);
}

// ---- prep: pack split-bf16 codebook fragments + exact tables into workspace ----
// frag-linear layout per 16-code tile j=c>>4 (512 dwords): half h (256 dwords),
// lane-slot l = (c&15) | (qid<<4) at l*4 dwords; k = 32h + 8*qid + t
__global__ void vq_prep(const float* __restrict__ weight, unsigned* __restrict__ ws) {
    const int c = blockIdx.x * 64 + threadIdx.x;    // 8 blocks x 64 = 512 codes
    const float* wr = weight + c * DIM;
    float wv[DIM];
    #pragma unroll
    for (int d = 0; d < DIM; d += 4) {
        float4 t4 = *(const float4*)&wr[d];
        wv[d] = t4.x; wv[d + 1] = t4.y; wv[d + 2] = t4.z; wv[d + 3] = t4.w;
    }
    float s; NP_SUMSQ64(wv, s);
    ((float*)(ws + WS_W2_OFF))[c] = s;              // exact pairwise ||w||^2
    float sa = 0.0f;
    #pragma unroll
    for (int d = 0; d < DIM; ++d) sa = __fadd_rn(sa, fabsf(wv[d]));
    ((float*)(ws + WS_SW_OFF))[c] = sa * 1.0002f + 1e-7f;   // sum|w| + slack

    const int tb = (c >> 4) * 512;
    const int ls = (c & 15) * 4;
    #pragma unroll
    for (int g = 0; g < 8; ++g) {                   // g = k/8
        int base = tb + (g >> 2) * 256 + (g & 3) * 64 + ls;
        unsigned hu[4], lu[4];
        #pragma unroll
        for (int p = 0; p < 4; ++p) {
            float e0 = wv[8 * g + 2 * p], e1 = wv[8 * g + 2 * p + 1];
            unsigned h0 = bf16rn(e0), h1 = bf16rn(e1);
            float r0 = __fsub_rn(e0, bf2f(h0));     // exact residual
            float r1 = __fsub_rn(e1, bf2f(h1));
            hu[p] = h0 | (h1 << 16);
            lu[p] = bf16rn(r0) | (bf16rn(r1) << 16);
        }
        *(uint4*)&ws[base] = make_uint4(hu[0], hu[1], hu[2], hu[3]);
        *(uint4*)&ws[WS_FRAG_LO + base] = make_uint4(lu[0], lu[1], lu[2], lu[3]);
    }
}

// ---- main: MFMA split-bf16 screen + tiny exact rescue, 2 blocks/CU ----
__global__ __launch_bounds__(512, 4) void vq_mfma2(const float* __restrict__ x_in,
                                                   const float* __restrict__ weight,
                                                   const unsigned* __restrict__ frg,
                                                   const float* __restrict__ w2g,
                                                   const float* __restrict__ swg,
                                                   double* __restrict__ lslots,
                                                   float* __restrict__ out) {
    __shared__ float xlds[TILE_R * RS];          // 69632 B fp32 x tile
    __shared__ float Arow[TILE_R];
    __shared__ float maxx[TILE_R];
    __shared__ int   cntL[TILE_R];
    __shared__ unsigned short listL[TILE_R * CAP];
    __shared__ int   ilds[TILE_R];
    __shared__ float wsum[8];
    // total ~77856 B -> 2 blocks/CU

    const int tid   = threadIdx.x;
    const int lane  = tid & 63;
    const int wid   = tid >> 6;        // 8 waves; wave owns rows [wbase, wbase+32)
    const int wbase = wid * 32;
    const int qid   = lane >> 4;       // lane quarter 0..3
    const int l15   = lane & 15;

    const int rowbase = blockIdx.x * TILE_R;
    const int b       = rowbase >> 12;
    const int hw0     = rowbase & 4095;
    const float* xb   = x_in + (size_t)b * CHW + hw0;

    // ---- stage x: float4 global loads along hw, transpose-write to LDS ----
    #pragma unroll
    for (int it = 0; it < 8; ++it) {
        int e = it * 512 + tid;
        int d = e >> 6, r4 = (e & 63) << 2;
        float4 v = *(const float4*)(xb + d * HW + r4);
        xlds[(r4 + 0) * RS + d] = v.x;
        xlds[(r4 + 1) * RS + d] = v.y;
        xlds[(r4 + 2) * RS + d] = v.z;
        xlds[(r4 + 3) * RS + d] = v.w;
    }
    if (tid < TILE_R) cntL[tid] = 0;
    __syncthreads();

    // ---- per-row A (pairwise, bit-exact) + maxabs ----
    if (tid < TILE_R) {
        const float* src = &xlds[tid * RS];
        float s; NP_SUMSQ64(src, s);
        Arow[tid] = s;
        float mx = 0.0f;
        #pragma unroll
        for (int d = 0; d < DIM; ++d) mx = fmaxf(mx, fabsf(src[d]));
        maxx[tid] = mx;
    }

    // ---- A fragments: hi + exact-residual lo, 2 row-tiles x 2 K-halves ----
    bf16x8 afh[2][2], afl[2][2];
    #pragma unroll
    for (int rt = 0; rt < 2; ++rt) {
        int r = wbase + 16 * rt + l15;
        #pragma unroll
        for (int h = 0; h < 2; ++h) {
            int kb = h * 32 + qid * 8;
            float4 xa = *(const float4*)&xlds[r * RS + kb];
            float4 xc = *(const float4*)&xlds[r * RS + kb + 4];
            float xs[8] = {xa.x, xa.y, xa.z, xa.w, xc.x, xc.y, xc.z, xc.w};
            union { unsigned u[4]; bf16x8 v; } ch, cl;
            #pragma unroll
            for (int p = 0; p < 4; ++p) {
                float e0 = xs[2 * p], e1 = xs[2 * p + 1];
                unsigned h0 = bf16rn(e0), h1 = bf16rn(e1);
                float r0 = __fsub_rn(e0, bf2f(h0));
                float r1 = __fsub_rn(e1, bf2f(h1));
                ch.u[p] = h0 | (h1 << 16);
                cl.u[p] = bf16rn(r0) | (bf16rn(r1) << 16);
            }
            afh[rt][h] = ch.v;
            afl[rt][h] = cl.v;
        }
    }
    __syncthreads();   // Arow/maxx/cntL ready

    float wk1r[2][4], tmin[2][4];
    #pragma unroll
    for (int rt = 0; rt < 2; ++rt)
        #pragma unroll
        for (int rg = 0; rg < 4; ++rg) {
            wk1r[rt][rg] = WK1S * maxx[wbase + 16 * rt + 4 * qid + rg];
            tmin[rt][rg] = 3.4e38f;
        }

    const unsigned* fh  = frg + lane * 4;
    const unsigned* flo = frg + WS_FRAG_LO + lane * 4;
    float swrun = 0.0f;

    for (int q = 0; q < 4; ++q) {                    // 4 chunks x 128 codes
        #pragma unroll
        for (int sc = 0; sc < 2; ++sc) {             // 2 sub-chunks x 64 codes
            f32x4 acc[2][4] = {};
            #pragma unroll
            for (int jx = 0; jx < 4; ++jx) {
                const int tb2 = ((q * 2 + sc) * 4 + jx) * 512;
                bf16x8 bh0 = *(const bf16x8*)&fh[tb2];
                bf16x8 bh1 = *(const bf16x8*)&fh[tb2 + 256];
                bf16x8 bl0 = *(const bf16x8*)&flo[tb2];
                bf16x8 bl1 = *(const bf16x8*)&flo[tb2 + 256];
                #pragma unroll
                for (int rt = 0; rt < 2; ++rt) {
                    acc[rt][jx] = __builtin_amdgcn_mfma_f32_16x16x32_bf16(afh[rt][0], bh0, acc[rt][jx], 0, 0, 0);
                    acc[rt][jx] = __builtin_amdgcn_mfma_f32_16x16x32_bf16(afh[rt][1], bh1, acc[rt][jx], 0, 0, 0);
                    acc[rt][jx] = __builtin_amdgcn_mfma_f32_16x16x32_bf16(afl[rt][0], bh0, acc[rt][jx], 0, 0, 0);
                    acc[rt][jx] = __builtin_amdgcn_mfma_f32_16x16x32_bf16(afl[rt][1], bh1, acc[rt][jx], 0, 0, 0);
                    acc[rt][jx] = __builtin_amdgcn_mfma_f32_16x16x32_bf16(afh[rt][0], bl0, acc[rt][jx], 0, 0, 0);
                    acc[rt][jx] = __builtin_amdgcn_mfma_f32_16x16x32_bf16(afh[rt][1], bl1, acc[rt][jx], 0, 0, 0);
                }
            }

            // ---- epilogue: t = w2/2 - m (dist = A + 2t monotone); mins; collect ----
            float tl[2][4], swv[4], swm = 0.0f;
            #pragma unroll
            for (int rt = 0; rt < 2; ++rt)
                #pragma unroll
                for (int rg = 0; rg < 4; ++rg) tl[rt][rg] = 3.4e38f;
            #pragma unroll
            for (int jx = 0; jx < 4; ++jx) {
                int c = q * 128 + (sc * 4 + jx) * 16 + l15;
                float w2hv = 0.5f * w2g[c];
                float sv = swg[c];
                swv[jx] = sv; swm = fmaxf(swm, sv);
                #pragma unroll
                for (int rt = 0; rt < 2; ++rt)
                    #pragma unroll
                    for (int rg = 0; rg < 4; ++rg) {
                        float t = __fsub_rn(w2hv, acc[rt][jx][rg]);
                        acc[rt][jx][rg] = t;
                        tl[rt][rg] = fminf(tl[rt][rg], t);
                    }
            }
            #pragma unroll
            for (int mk = 1; mk <= 8; mk <<= 1) {
                #pragma unroll
                for (int rt = 0; rt < 2; ++rt)
                    #pragma unroll
                    for (int rg = 0; rg < 4; ++rg)
                        tl[rt][rg] = fminf(tl[rt][rg], __shfl_xor(tl[rt][rg], mk));
                swm = fmaxf(swm, __shfl_xor(swm, mk));
            }
            swrun = fmaxf(swrun, swm);
            #pragma unroll
            for (int rt = 0; rt < 2; ++rt)
                #pragma unroll
                for (int rg = 0; rg < 4; ++rg)
                    tmin[rt][rg] = fminf(tmin[rt][rg], tl[rt][rg]);

            #pragma unroll
            for (int rt = 0; rt < 2; ++rt)
                #pragma unroll
                for (int rg = 0; rg < 4; ++rg) {
                    float gate = __fmaf_rn(wk1r[rt][rg], swm + swrun, tmin[rt][rg] + WK2S);
                    if (tl[rt][rg] <= gate) {
                        #pragma unroll
                        for (int jx = 0; jx < 4; ++jx) {
                            float thr = __fmaf_rn(wk1r[rt][rg], swv[jx] + swrun, tmin[rt][rg] + WK2S);
                            if (acc[rt][jx][rg] <= thr) {
                                int r = wbase + 16 * rt + 4 * qid + rg;
                                int c = q * 128 + (sc * 4 + jx) * 16 + l15;
                                int cn = atomicAdd(&cntL[r], 1);
                                if (cn < CAP) listL[r * CAP + cn] = (unsigned short)c;
                            }
                        }
                    }
                }
        }
    }

    __syncthreads();   // candidate lists visible

    // ---- rescue: cnt==1 -> decided; else exact fp32 chain, smallest-idx ties ----
    if (lane < 32) {
        const int r   = wbase + lane;
        const int cnt = cntL[r];
        if (cnt >= 1 && cnt <= CAP) {
            int bi;
            if (cnt == 1) {
                bi = listL[r * CAP];
            } else {
                const float* xr = &xlds[r * RS];
                const float  A  = Arow[r];
                float bd = 3.4e38f; bi = 1 << 30;
                for (int t2 = 0; t2 < cnt; ++t2) {
                    int c = listL[r * CAP + t2];
                    float d2 = evald(xr, weight + c * DIM, A, w2g[c]);
                    if (d2 < bd || (d2 == bd && c < bi)) { bd = d2; bi = c; }
                }
            }
            ilds[r] = bi;
            out[IDX_OFF + rowbase + r] = (float)bi;
        }
    }
    // cooperative exact full scan for overflow rows (rare; correctness backstop)
    for (int rr = 0; rr < 32; ++rr) {
        int r   = wbase + rr;
        int cnt = cntL[r];
        if (cnt < 1 || cnt > CAP) {
            const float* xr = &xlds[r * RS];
            const float  A  = Arow[r];
            float bd = 3.4e38f; int bi = 1 << 30;
            #pragma unroll
            for (int t2 = 0; t2 < 8; ++t2) {
                int c = t2 * 64 + lane;
                float d2 = evald(xr, weight + c * DIM, A, w2g[c]);
                if (d2 < bd || (d2 == bd && c < bi)) { bd = d2; bi = c; }
            }
            ull key = ((ull)__float_as_uint(bd) << 32) | (unsigned)bi;
            #pragma unroll
            for (int mk = 1; mk <= 32; mk <<= 1) {
                ull o = __shfl_xor(key, mk);
                if (o < key) key = o;
            }
            if (lane == 0) {
                int bi2 = (int)(key & 0xffffffffu);
                ilds[r] = bi2;
                out[IDX_OFF + rowbase + r] = (float)bi2;
            }
        }
    }
    __syncthreads();   // ilds visible

    // ---- quantize epilogue + loss (exact reference semantics, validated) ----
    const int row = wbase + (lane & 31);
    const int dh  = (lane >> 5) << 5;           // 0 or 32
    const float* xr2 = &xlds[row * RS + dh];
    const float* wr2 = weight + ilds[row] * DIM + dh;
    float* ob = out + Q_OFF + (size_t)b * CHW + hw0 + row;
    float lsum = 0.0f;
    #pragma unroll
    for (int t2 = 0; t2 < 8; ++t2) {
        float4 xv  = *(const float4*)&xr2[4 * t2];
        float4 wv2 = *(const float4*)&wr2[4 * t2];
        float dd;
        dd = __fsub_rn(wv2.x, xv.x); ob[(size_t)(dh + 4 * t2 + 0) * HW] = __fadd_rn(xv.x, dd); lsum = fmaf(dd, dd, lsum);
        dd = __fsub_rn(wv2.y, xv.y); ob[(size_t)(dh + 4 * t2 + 1) * HW] = __fadd_rn(xv.y, dd); lsum = fmaf(dd, dd, lsum);
        dd = __fsub_rn(wv2.z, xv.z); ob[(size_t)(dh + 4 * t2 + 2) * HW] = __fadd_rn(xv.z, dd); lsum = fmaf(dd, dd, lsum);
        dd = __fsub_rn(wv2.w, xv.w); ob[(size_t)(dh + 4 * t2 + 3) * HW] = __fadd_rn(xv.w, dd); lsum = fmaf(dd, dd, lsum);
    }
    #pragma unroll
    for (int off = 32; off > 0; off >>= 1) lsum += __shfl_down(lsum, off);
    if (lane == 0) wsum[wid] = lsum;
    __syncthreads();
    if (tid == 0) {
        double s = 0.0;
        #pragma unroll
        for (int i = 0; i < 8; ++i) s += (double)wsum[i];
        lslots[blockIdx.x] = s;
    }
}

__global__ void vq_finalize4(const double* __restrict__ lslots,
                             float* __restrict__ out) {
    double s = 0.0;
    for (int i = threadIdx.x; i < 512; i += 64) s += lslots[i];
    #pragma unroll
    for (int off = 32; off > 0; off >>= 1) s += __shfl_down(s, off);
    if (threadIdx.x == 0) {
        double m = s / 8388608.0;
        out[LOSS_OFF] = (float)(m + 0.25 * m);   // q_latent + 0.25 * e_latent
    }
}

// ================= R1 fallback (validated): used if ws in [4KB, WS_NEED) ======
#define R1RS      68
#define R1CAP     16
#define WK1       0.018f
#define WK2       2.5e-4f

__global__ __launch_bounds__(512, 2) void vq_mfma(const float* __restrict__ x_in,
                                                  const float* __restrict__ weight,
                                                  double* __restrict__ lslots,
                                                  float* __restrict__ out) {
    __shared__ float xlds[TILE_R * R1RS];
    __shared__ unsigned bfr[NUM_K * 32];
    __shared__ float w2all[NUM_K];
    __shared__ float w2h[NUM_K];
    __shared__ float sumw[NUM_K];
    __shared__ float Arow[TILE_R];
    __shared__ float maxx[TILE_R];
    __shared__ int   cntL[TILE_R];
    __shared__ unsigned short listL[TILE_R * R1CAP];
    __shared__ int   ilds[TILE_R];
    __shared__ float wsum[8];

    const int tid   = threadIdx.x;
    const int lane  = tid & 63;
    const int wid   = tid >> 6;
    const int wbase = wid * 32;
    const int qid   = lane >> 4;
    const int l15   = lane & 15;

    const int rowbase = blockIdx.x * TILE_R;
    const int b       = rowbase >> 12;
    const int hw0     = rowbase & 4095;
    const float* xb   = x_in + (size_t)b * CHW + hw0;

    #pragma unroll
    for (int it = 0; it < 8; ++it) {
        int id  = it * 512 + tid;
        int row = id & 255, g = id >> 8;
        const float* gp = xb + g * 4 * HW + row;
        float4 v = make_float4(gp[0], gp[HW], gp[2 * HW], gp[3 * HW]);
        *(float4*)&xlds[row * R1RS + g * 4] = v;
    }
    {
        const int c = tid;
        const float* wr = weight + c * DIM;
        float wv[DIM];
        #pragma unroll
        for (int d = 0; d < DIM; d += 4) {
            float4 t4 = *(const float4*)&wr[d];
            wv[d] = t4.x; wv[d + 1] = t4.y; wv[d + 2] = t4.z; wv[d + 3] = t4.w;
        }
        float s; NP_SUMSQ64(wv, s);
        w2all[c] = s;
        w2h[c]   = 0.5f * s;
        float sa = 0.0f;
        #pragma unroll
        for (int d = 0; d < DIM; ++d) sa = __fadd_rn(sa, fabsf(wv[d]));
        sumw[c] = sa * 1.0002f + 1e-7f;
        const int tb = (c >> 4) * 512;
        const int ls = (c & 15) * 4;
        #pragma unroll
        for (int g = 0; g < 8; ++g) {
            int base = tb + (g >> 2) * 256 + (g & 3) * 64 + ls;
            uint4 pw = make_uint4(pk2(wv[8 * g + 0], wv[8 * g + 1]),
                                  pk2(wv[8 * g + 2], wv[8 * g + 3]),
                                  pk2(wv[8 * g + 4], wv[8 * g + 5]),
                                  pk2(wv[8 * g + 6], wv[8 * g + 7]));
            *(uint4*)&bfr[base] = pw;
        }
    }
    if (tid < TILE_R) cntL[tid] = 0;
    __syncthreads();

    if (tid < TILE_R) {
        const float* src = &xlds[tid * R1RS];
        float s; NP_SUMSQ64(src, s);
        Arow[tid] = s;
        float mx = 0.0f;
        #pragma unroll
        for (int d = 0; d < DIM; ++d) mx = fmaxf(mx, fabsf(src[d]));
        maxx[tid] = mx;
    }

    bf16x8 afr[2][2];
    #pragma unroll
    for (int rt = 0; rt < 2; ++rt) {
        int r = wbase + 16 * rt + l15;
        #pragma unroll
        for (int h = 0; h < 2; ++h) {
            int kb = h * 32 + qid * 8;
            float4 xa  = *(const float4*)&xlds[r * R1RS + kb];
            float4 xc  = *(const float4*)&xlds[r * R1RS + kb + 4];
            union { unsigned u[4]; bf16x8 v; } cv;
            cv.u[0] = pk2(xa.x, xa.y); cv.u[1] = pk2(xa.z, xa.w);
            cv.u[2] = pk2(xc.x, xc.y); cv.u[3] = pk2(xc.z, xc.w);
            afr[rt][h] = cv.v;
        }
    }
    __syncthreads();

    float wk1r[2][4], tmin[2][4];
    #pragma unroll
    for (int rt = 0; rt < 2; ++rt)
        #pragma unroll
        for (int rg = 0; rg < 4; ++rg) {
            wk1r[rt][rg] = WK1 * maxx[wbase + 16 * rt + 4 * qid + rg];
            tmin[rt][rg] = 3.4e38f;
        }

    const int lane4 = lane * 4;
    for (int q = 0; q < 4; ++q) {
        f32x4 acc[2][8] = {};
        #pragma unroll
        for (int j = 0; j < 8; ++j) {
            int tb2 = (q * 8 + j) * 512;
            bf16x8 bb0 = *(const bf16x8*)&bfr[tb2 + lane4];
            bf16x8 bb1 = *(const bf16x8*)&bfr[tb2 + 256 + lane4];
            acc[0][j] = __builtin_amdgcn_mfma_f32_16x16x32_bf16(afr[0][0], bb0, acc[0][j], 0, 0, 0);
            acc[0][j] = __builtin_amdgcn_mfma_f32_16x16x32_bf16(afr[0][1], bb1, acc[0][j], 0, 0, 0);
            acc[1][j] = __builtin_amdgcn_mfma_f32_16x16x32_bf16(afr[1][0], bb0, acc[1][j], 0, 0, 0);
            acc[1][j] = __builtin_amdgcn_mfma_f32_16x16x32_bf16(afr[1][1], bb1, acc[1][j], 0, 0, 0);
        }

        const int k0 = q * 128;
        float swv[8], tl[2][4];
        #pragma unroll
        for (int rt = 0; rt < 2; ++rt)
            #pragma unroll
            for (int rg = 0; rg < 4; ++rg) tl[rt][rg] = 3.4e38f;
        #pragma unroll
        for (int j = 0; j < 8; ++j) {
            int c = k0 + j * 16 + l15;
            float w2hv = w2h[c];
            swv[j] = sumw[c];
            #pragma unroll
            for (int rt = 0; rt < 2; ++rt)
                #pragma unroll
                for (int rg = 0; rg < 4; ++rg) {
                    float t = w2hv - acc[rt][j][rg];
                    acc[rt][j][rg] = t;
                    tl[rt][rg] = fminf(tl[rt][rg], t);
                }
        }
        #pragma unroll
        for (int mk = 1; mk <= 8; mk <<= 1)
            #pragma unroll
            for (int rt = 0; rt < 2; ++rt)
                #pragma unroll
                for (int rg = 0; rg < 4; ++rg)
                    tl[rt][rg] = fminf(tl[rt][rg], __shfl_xor(tl[rt][rg], mk));
        float thr0[2][4];
        #pragma unroll
        for (int rt = 0; rt < 2; ++rt)
            #pragma unroll
            for (int rg = 0; rg < 4; ++rg) {
                tmin[rt][rg] = fminf(tmin[rt][rg], tl[rt][rg]);
                thr0[rt][rg] = tmin[rt][rg] + WK2;
            }
        float swmax = swv[0];
        #pragma unroll
        for (int j = 1; j < 8; ++j) swmax = fmaxf(swmax, swv[j]);

        #pragma unroll
        for (int rt = 0; rt < 2; ++rt)
            #pragma unroll
            for (int rg = 0; rg < 4; ++rg) {
                if (tl[rt][rg] <= __fmaf_rn(wk1r[rt][rg], swmax, thr0[rt][rg])) {
                    #pragma unroll
                    for (int j = 0; j < 8; ++j) {
                        if (acc[rt][j][rg] <= __fmaf_rn(wk1r[rt][rg], swv[j], thr0[rt][rg])) {
                            int r  = wbase + 16 * rt + 4 * qid + rg;
                            int c  = k0 + j * 16 + l15;
                            int cn = atomicAdd(&cntL[r], 1);
                            if (cn < R1CAP) listL[r * R1CAP + cn] = (unsigned short)c;
                        }
                    }
                }
            }
    }

    __syncthreads();

    if (lane < 32) {
        const int r   = wbase + lane;
        const int cnt = cntL[r];
        if (cnt >= 1 && cnt <= R1CAP) {
            const float* xr = &xlds[r * R1RS];
            const float  A  = Arow[r];
            float bd = 3.4e38f; int bi = 1 << 30;
            for (int t2 = 0; t2 < cnt; ++t2) {
                int c = listL[r * R1CAP + t2];
                float d2 = evald(xr, weight + c * DIM, A, w2all[c]);
                if (d2 < bd || (d2 == bd && c < bi)) { bd = d2; bi = c; }
            }
            ilds[r] = bi;
            out[IDX_OFF + rowbase + r] = (float)bi;
        }
    }
    for (int rr = 0; rr < 32; ++rr) {
        int r   = wbase + rr;
        int cnt = cntL[r];
        if (cnt < 1 || cnt > R1CAP) {
            const float* xr = &xlds[r * R1RS];
            const float  A  = Arow[r];
            float bd = 3.4e38f; int bi = 1 << 30;
            #pragma unroll
            for (int t2 = 0; t2 < 8; ++t2) {
                int c = t2 * 64 + lane;
                float d2 = evald(xr, weight + c * DIM, A, w2all[c]);
                if (d2 < bd || (d2 == bd && c < bi)) { bd = d2; bi = c; }
            }
            ull key = ((ull)__float_as_uint(bd) << 32) | (unsigned)bi;
            #pragma unroll
            for (int mk = 1; mk <= 32; mk <<= 1) {
                ull o = __shfl_xor(key, mk);
                if (o < key) key = o;
            }
            if (lane == 0) {
                int bi2 = (int)(key & 0xffffffffu);
                ilds[r] = bi2;
                out[IDX_OFF + rowbase + r] = (float)bi2;
            }
        }
    }
    __syncthreads();

    const int row = wbase + (lane & 31);
    const int dh  = (lane >> 5) << 5;
    const float* xr2 = &xlds[row * R1RS + dh];
    const float* wr2 = weight + ilds[row] * DIM + dh;
    float* ob = out + Q_OFF + (size_t)b * CHW + hw0 + row;
    float lsum = 0.0f;
    #pragma unroll
    for (int t2 = 0; t2 < 8; ++t2) {
        float4 xv  = *(const float4*)&xr2[4 * t2];
        float4 wv2 = *(const float4*)&wr2[4 * t2];
        float dd;
        dd = __fsub_rn(wv2.x, xv.x); ob[(size_t)(dh + 4 * t2 + 0) * HW] = __fadd_rn(xv.x, dd); lsum = fmaf(dd, dd, lsum);
        dd = __fsub_rn(wv2.y, xv.y); ob[(size_t)(dh + 4 * t2 + 1) * HW] = __fadd_rn(xv.y, dd); lsum = fmaf(dd, dd, lsum);
        dd = __fsub_rn(wv2.z, xv.z); ob[(size_t)(dh + 4 * t2 + 2) * HW] = __fadd_rn(xv.z, dd); lsum = fmaf(dd, dd, lsum);
        dd = __fsub_rn(wv2.w, xv.w); ob[(size_t)(dh + 4 * t2 + 3) * HW] = __fadd_rn(xv.w, dd); lsum = fmaf(dd, dd, lsum);
    }
    #pragma unroll
    for (int off = 32; off > 0; off >>= 1) lsum += __shfl_down(lsum, off);
    if (lane == 0) wsum[wid] = lsum;
    __syncthreads();
    if (tid == 0) {
        double s = 0.0;
        #pragma unroll
        for (int i = 0; i < 8; ++i) s += (double)wsum[i];
        lslots[blockIdx.x] = s;
    }
}

// ---------------- scalar fallback (validated), used only if ws tiny ----------
__global__ void vq_zero(double* __restrict__ loss_acc) {
    if (threadIdx.x == 0) *loss_acc = 0.0;
}

__global__ __launch_bounds__(256) void vq_fused(const float* __restrict__ x_in,
                                                const float* __restrict__ weight,
                                                double* __restrict__ loss_acc,
                                                float* __restrict__ out) {
    __shared__ float w2s[NUM_K];
    for (int k = threadIdx.x; k < NUM_K; k += 256) {
        const float* wk = weight + k * DIM;
        float s; NP_SUMSQ64(wk, s);
        w2s[k] = s;
    }
    __syncthreads();

    const int n  = blockIdx.x * 256 + threadIdx.x;
    const int b  = n >> 12;
    const int hw = n & 4095;
    const float* xp = x_in + b * CHW + hw;
    float x[DIM];
    #pragma unroll
    for (int d = 0; d < DIM; ++d) x[d] = xp[d * HW];

    float A; NP_SUMSQ64(x, A);

    float best = 3.4e38f;
    int   bi   = 0;
    for (int k = 0; k < NUM_K; k += 4) {
        const float* w0 = weight + k * DIM;
        float m0 = 0.f, m1 = 0.f, m2 = 0.f, m3 = 0.f;
        #pragma unroll
        for (int d = 0; d < DIM; ++d) {
            float xd = x[d];
            m0 = __fmaf_rn(xd, w0[d],           m0);
            m1 = __fmaf_rn(xd, w0[DIM + d],     m1);
            m2 = __fmaf_rn(xd, w0[2 * DIM + d], m2);
            m3 = __fmaf_rn(xd, w0[3 * DIM + d], m3);
        }
        float d0 = __fadd_rn(__fsub_rn(A, __fmul_rn(2.0f, m0)), w2s[k]);
        float d1 = __fadd_rn(__fsub_rn(A, __fmul_rn(2.0f, m1)), w2s[k + 1]);
        float d2 = __fadd_rn(__fsub_rn(A, __fmul_rn(2.0f, m2)), w2s[k + 2]);
        float d3 = __fadd_rn(__fsub_rn(A, __fmul_rn(2.0f, m3)), w2s[k + 3]);
        if (d0 < best) { best = d0; bi = k; }
        if (d1 < best) { best = d1; bi = k + 1; }
        if (d2 < best) { best = d2; bi = k + 2; }
        if (d3 < best) { best = d3; bi = k + 3; }
    }
    const int idx = bi;

    out[IDX_OFF + n] = (float)idx;
    const float* qrow = weight + idx * DIM;
    float* oq = out + Q_OFF + b * CHW + hw;
    float lsum = 0.0f;
    #pragma unroll
    for (int d = 0; d < DIM; ++d) {
        float xd   = xp[d * HW];
        float diff = __fsub_rn(qrow[d], xd);
        oq[d * HW] = __fadd_rn(xd, diff);
        lsum = fmaf(diff, diff, lsum);
    }
    #pragma unroll
    for (int off = 32; off > 0; off >>= 1) lsum += __shfl_down(lsum, off);
    __shared__ float wsum[4];
    if ((threadIdx.x & 63) == 0) wsum[threadIdx.x >> 6] = lsum;
    __syncthreads();
    if (threadIdx.x == 0)
        atomicAdd(loss_acc, (double)((wsum[0] + wsum[1]) + (wsum[2] + wsum[3])));
}

__global__ void vq_finalize(const double* __restrict__ loss_acc,
                            float* __restrict__ out) {
    double m = *loss_acc / 8388608.0;
    out[LOSS_OFF] = (float)(m + 0.25 * m);
}

extern "C" void kernel_launch(void* const* d_in, const int* in_sizes, int n_in,
                              void* d_out, int out_size, void* d_ws, size_t ws_size,
                              hipStream_t stream) {
    const float* x = (const float*)d_in[0];    // inputs  [32,64,64,64] NCHW fp32
    const float* w = (const float*)d_in[1];    // weight  [512,64] fp32
    float* out = (float*)d_out;

    if (ws_size >= WS_NEED) {
        unsigned* ws32 = (unsigned*)d_ws;
        const float* w2g = (const float*)(ws32 + WS_W2_OFF);
        const float* swg = (const float*)(ws32 + WS_SW_OFF);
        double* lslots = (double*)((char*)d_ws + WS_LSL_BYTE);
        vq_prep<<<8, 64, 0, stream>>>(w, ws32);
        vq_mfma2<<<N_ROWS / TILE_R, 512, 0, stream>>>(x, w, ws32, w2g, swg, lslots, out);
        vq_finalize4<<<1, 64, 0, stream>>>(lslots, out);
    } else if (ws_size >= 512 * sizeof(double)) {
        double* lslots = (double*)d_ws;
        vq_mfma<<<N_ROWS / TILE_R, 512, 0, stream>>>(x, w, lslots, out);
        vq_finalize4<<<1, 64, 0, stream>>>(lslots, out);
    } else {
        double* loss_acc = (double*)d_ws;
        vq_zero<<<1, 64, 0, stream>>>(loss_acc);
        vq_fused<<<512, 256, 0, stream>>>(x, w, loss_acc, out);
        vq_finalize<<<1, 1, 0, stream>>>(loss_acc, out);
    }
}